// Round 16
// baseline (252.464 us; speedup 1.0000x reference)
//
#include <hip/hip_runtime.h>
#include <hip/hip_bf16.h>
#include <stdint.h>

#define BATCH 16384
#define D 1024
#define NCLS 1000
#define NPROTO 5000
#define NPROTO_PAD 5120
#define NGRP 320              // proto col-groups of 16
#define NRGRP 1024            // batch row-groups of 16
#define BM 128                // rows per block
#define COLHALF 2560
#define NCH 5                 // chunks of 512 cols per half
#define NKT 32
#define KT_B (NGRP * 512)     // pbf elems per kt
#define KT_A (NRGRP * 512)    // abf elems per kt

typedef float f32x4 __attribute__((ext_vector_type(4)));
typedef __bf16 bf16x8 __attribute__((ext_vector_type(8)));
typedef unsigned short u16x8 __attribute__((ext_vector_type(8)));

__device__ __forceinline__ unsigned short f2bf(float x) {
    unsigned u = __float_as_uint(x);
    u += 0x7FFFu + ((u >> 16) & 1u);   // RNE
    return (unsigned short)(u >> 16);
}

// ---------- normalize rows of z and P to bf16, MFMA-fragment-packed --------
// abf[kt][rgrp][lane][8]: row = rgrp*16 + (lane&15), k = kt*32 + (lane>>4)*8+e
// pbf[kt][grp][lane][8]:  col = grp*16 + (lane&15), same k mapping
__global__ __launch_bounds__(256) void k_prep(
        const float* __restrict__ z, const float* __restrict__ P,
        unsigned short* __restrict__ abf, unsigned short* __restrict__ pbf) {
    const int b = blockIdx.x;
    const int t = threadIdx.x;
    const int e0 = 4 * t;
    const int kt = e0 >> 5;
    const int lk = (e0 >> 3) & 3;
    const int e = e0 & 7;
    const float* src = nullptr;
    unsigned short* dst;
    if (b < BATCH) {
        src = z + (size_t)b * D;
        dst = abf + (((size_t)kt * NRGRP + (b >> 4)) * 64 + (b & 15) + 16 * lk) * 8 + e;
    } else {
        const int r = b - BATCH;
        dst = pbf + (((size_t)kt * NGRP + (r >> 4)) * 64 + (r & 15) + 16 * lk) * 8 + e;
        if (r < NPROTO) src = P + (size_t)r * D;
    }
    if (src == nullptr) {                 // padded proto row -> zeros
        *(ushort4*)dst = make_ushort4(0, 0, 0, 0);
        return;
    }
    float4 v = ((const float4*)src)[t];
    float ss = v.x * v.x + v.y * v.y + v.z * v.z + v.w * v.w;
    #pragma unroll
    for (int o = 32; o >= 1; o >>= 1) ss += __shfl_xor(ss, o);
    __shared__ float red[4];
    const int wave = t >> 6;
    if ((t & 63) == 0) red[wave] = ss;
    __syncthreads();
    const float s = red[0] + red[1] + red[2] + red[3];
    const float inv = 1.0f / fmaxf(sqrtf(s), 1e-12f);
    ushort4 o4;
    o4.x = f2bf(v.x * inv); o4.y = f2bf(v.y * inv);
    o4.z = f2bf(v.z * inv); o4.w = f2bf(v.w * inv);
    *(ushort4*)dst = o4;
}

#define MM(A, B, C) __builtin_amdgcn_mfma_f32_16x16x32_bf16(A, B, C, 0, 0, 0)

// ---------- BM=128 GEMM, K-split A in LDS, B streamed (no duplication) ----
// 256 blocks (128 row-tiles x 2 col-halves) x 1024 threads (16 waves, 4/SIMD).
// Wave tile 128x32: all waves share A (LDS), own 32 distinct cols (2 loads/kt)
// -> per-CU VMEM = B 5.25MB + A-restage 1.28MB (the 27 B/cyc bus is the wall).
// LDS holds one K-half of A (16 kt = 128 KB); restage between kh phases:
// wave w reloads K-tile kh*16+w (8x16B coalesced loads pre-issued, then
// barrier -> ds_write -> barrier). K-loop itself is barrier-free.
__global__ __launch_bounds__(1024, 4) void k_gemm(
        const unsigned short* __restrict__ abf,
        const unsigned short* __restrict__ pbf,
        const int* __restrict__ y,
        float* __restrict__ outP, float* __restrict__ outN) {
    __shared__ __align__(16) unsigned short LA[16][8][64][8];   // 128 KiB
    __shared__ float redP[16][128];                             // 8 KiB
    __shared__ float redN[16][128];                             // 8 KiB

    const int t = threadIdx.x;
    const int w = t >> 6;                // wave 0..15
    const int lane = t & 63;
    const int lm = lane & 15, lk = lane >> 4;
    const int bid = blockIdx.x;
    const int rowbase = (bid >> 1) * BM;
    const int ch = bid & 1;              // col-half
    const int rgrp0 = rowbase >> 4;

    redP[w][lane] = -INFINITY;
    redP[w][lane + 64] = -INFINITY;
    redN[w][lane] = -INFINITY;
    redN[w][lane + 64] = -INFINITY;

    // restage: wave w handles K-tile (KH*16 + w); lane covers 8 x 16B,
    // identical linear mapping on both sides -> coalesced + conflict-free.
    unsigned short* const laf = &LA[0][0][0][0];
#define RESTAGE_LOAD(KH)                                                     \
    const unsigned short* rs_ =                                              \
        abf + ((size_t)((KH) * 16 + w) * NRGRP + rgrp0) * 512 + lane * 8;    \
    u16x8 tmp0 = *(const u16x8*)(rs_);                                       \
    u16x8 tmp1 = *(const u16x8*)(rs_ + 512);                                 \
    u16x8 tmp2 = *(const u16x8*)(rs_ + 1024);                                \
    u16x8 tmp3 = *(const u16x8*)(rs_ + 1536);                                \
    u16x8 tmp4 = *(const u16x8*)(rs_ + 2048);                                \
    u16x8 tmp5 = *(const u16x8*)(rs_ + 2560);                                \
    u16x8 tmp6 = *(const u16x8*)(rs_ + 3072);                                \
    u16x8 tmp7 = *(const u16x8*)(rs_ + 3584)
#define RESTAGE_WRITE() do {                                                 \
    unsigned short* wd_ = laf + (size_t)w * 4096 + lane * 8;                 \
    *(u16x8*)(wd_) = tmp0;                                                   \
    *(u16x8*)(wd_ + 512) = tmp1;                                             \
    *(u16x8*)(wd_ + 1024) = tmp2;                                            \
    *(u16x8*)(wd_ + 1536) = tmp3;                                            \
    *(u16x8*)(wd_ + 2048) = tmp4;                                            \
    *(u16x8*)(wd_ + 2560) = tmp5;                                            \
    *(u16x8*)(wd_ + 3072) = tmp6;                                            \
    *(u16x8*)(wd_ + 3584) = tmp7;                                            \
} while (0)

    // initial stage of kh=0
    {
        RESTAGE_LOAD(0);
        RESTAGE_WRITE();
    }
    __syncthreads();

    #pragma unroll 1
    for (int c = 0; c < NCH; ++c) {
        const unsigned short* pBc =
            pbf + ((size_t)(ch * 160 + c * 32 + w * 2) * 64 + lane) * 8;

        f32x4 acc[8][2];
        #pragma unroll
        for (int mi = 0; mi < 8; ++mi)
            #pragma unroll
            for (int ni = 0; ni < 2; ++ni) {
                f32x4 z4 = {0.0f, 0.0f, 0.0f, 0.0f};
                acc[mi][ni] = z4;
            }

        #pragma unroll 1
        for (int kh = 0; kh < 2; ++kh) {
            // barrier-free 16-kt loop over this K-half
            #pragma unroll 1
            for (int kt = 0; kt < 16; ++kt) {
                const unsigned short* q = pBc + (size_t)(kh * 16 + kt) * KT_B;
                const bf16x8 b0 = *(const bf16x8*)(q);
                const bf16x8 b1 = *(const bf16x8*)(q + 512);
                const bf16x8 a0 = *(const bf16x8*)&LA[kt][0][lane][0];
                const bf16x8 a1 = *(const bf16x8*)&LA[kt][1][lane][0];
                const bf16x8 a2 = *(const bf16x8*)&LA[kt][2][lane][0];
                const bf16x8 a3 = *(const bf16x8*)&LA[kt][3][lane][0];
                acc[0][0] = MM(a0, b0, acc[0][0]);
                acc[0][1] = MM(a0, b1, acc[0][1]);
                acc[1][0] = MM(a1, b0, acc[1][0]);
                acc[1][1] = MM(a1, b1, acc[1][1]);
                acc[2][0] = MM(a2, b0, acc[2][0]);
                acc[2][1] = MM(a2, b1, acc[2][1]);
                acc[3][0] = MM(a3, b0, acc[3][0]);
                acc[3][1] = MM(a3, b1, acc[3][1]);
                const bf16x8 a4 = *(const bf16x8*)&LA[kt][4][lane][0];
                const bf16x8 a5 = *(const bf16x8*)&LA[kt][5][lane][0];
                const bf16x8 a6 = *(const bf16x8*)&LA[kt][6][lane][0];
                const bf16x8 a7 = *(const bf16x8*)&LA[kt][7][lane][0];
                acc[4][0] = MM(a4, b0, acc[4][0]);
                acc[4][1] = MM(a4, b1, acc[4][1]);
                acc[5][0] = MM(a5, b0, acc[5][0]);
                acc[5][1] = MM(a5, b1, acc[5][1]);
                acc[6][0] = MM(a6, b0, acc[6][0]);
                acc[6][1] = MM(a6, b1, acc[6][1]);
                acc[7][0] = MM(a7, b0, acc[7][0]);
                acc[7][1] = MM(a7, b1, acc[7][1]);
            }
            // restage next K-half (phases 0..8 of 10)
            if (c * 2 + kh < 2 * NCH - 1) {
                RESTAGE_LOAD(kh ^ 1);     // loads in flight during barrier
                __syncthreads();          // all waves done reading LA
                RESTAGE_WRITE();
                __syncthreads();          // LA ready
            }
        }

        // merge chunk into LDS-held pos/neg maxes (scalar transients only)
        #pragma unroll
        for (int mi = 0; mi < 8; ++mi) {
            #pragma unroll
            for (int r = 0; r < 4; ++r) {
                const int row = mi * 16 + lk * 4 + r;        // 0..127
                const unsigned yv = (unsigned)y[rowbase + row];
                float pm = -INFINITY, nm = -INFINITY;
                #pragma unroll
                for (int ni = 0; ni < 2; ++ni) {
                    const unsigned col =
                        (unsigned)(ch * COLHALF + c * 512 + w * 32 + ni * 16 + lm);
                    const unsigned lbl = __umulhi(col, 0xCCCCCCCDu) >> 2;  // /5
                    const float v = acc[mi][ni][r];
                    const bool same = (lbl == yv);
                    pm = same ? fmaxf(pm, v) : pm;
                    nm = (!same && col < NPROTO) ? fmaxf(nm, v) : nm;
                }
                #pragma unroll
                for (int off = 1; off < 16; off <<= 1) {
                    pm = fmaxf(pm, __shfl_xor(pm, off));
                    nm = fmaxf(nm, __shfl_xor(nm, off));
                }
                if (lm == 0) {   // lanes 0,16,32,48 -> 4 distinct rows
                    redP[w][row] = fmaxf(redP[w][row], pm);
                    redN[w][row] = fmaxf(redN[w][row], nm);
                }
            }
        }
    }

    __syncthreads();
    // merge the 16 waves; write per-col-half buffers (no atomics)
    if (t < 128) {
        float p = redP[0][t], n = redN[0][t];
        #pragma unroll
        for (int ww = 1; ww < 16; ++ww) {
            p = fmaxf(p, redP[ww][t]);
            n = fmaxf(n, redN[ww][t]);
        }
        outP[(size_t)ch * BATCH + rowbase + t] = p;
        outN[(size_t)ch * BATCH + rowbase + t] = n;
    }
#undef RESTAGE_LOAD
#undef RESTAGE_WRITE
}

// ---------- combine the two col-halves ----------
__global__ __launch_bounds__(256) void k_finish(
        const float* __restrict__ outP, const float* __restrict__ outN,
        float* __restrict__ out) {
    const int i = blockIdx.x * 256 + threadIdx.x;
    if (i < BATCH) {
        out[i] = fmaxf(outP[i], outP[BATCH + i]);
        out[BATCH + i] = fmaxf(outN[i], outN[BATCH + i]);
    }
}

extern "C" void kernel_launch(void* const* d_in, const int* in_sizes, int n_in,
                              void* d_out, int out_size, void* d_ws, size_t ws_size,
                              hipStream_t stream) {
    const float* z = (const float*)d_in[0];
    const int*   y = (const int*)d_in[1];
    const float* P = (const float*)d_in[2];

    // ws: abf 33.5MB | pbf 10.5MB | outP 128KB | outN 128KB
    unsigned short* abf = (unsigned short*)d_ws;
    unsigned short* pbf = abf + (size_t)NKT * KT_A;
    float* outP = (float*)(pbf + (size_t)NKT * KT_B);
    float* outN = outP + 2 * BATCH;
    float* out = (float*)d_out;

    k_prep<<<BATCH + NPROTO_PAD, 256, 0, stream>>>(z, P, abf, pbf);
    k_gemm<<<256, 1024, 0, stream>>>(abf, pbf, y, outP, outN);
    k_finish<<<BATCH / 256, 256, 0, stream>>>(outP, outN, out);
}